// Round 2
// baseline (144.651 us; speedup 1.0000x reference)
//
#include <hip/hip_runtime.h>
#include <math.h>

// SO3 convolution lmax=2, atom-centric two-phase:
//   phase A (tiny int kernels): CSR-sort edges by destination atom idx_i
//     hist -> single-block scan -> scatter  (rebuilt every call; inputs are
//     restored pristine before each timed launch so this is identical work)
//   phase B: one block (128 threads = 2 waves) per atom; loop incident edges,
//     per-edge M[9][9] = sum_k cg_val[k]*Y[i2[k]] at (i3[k],i1[k]) built in LDS,
//     dense 9x9 register contraction, per-l radial filter, accumulate acc[9],
//     write output ONCE (no float atomics anywhere, no output memset needed).

#define S9    9
#define NF    128
#define NRAD  20
#define CHUNK 16

// ---------- CSR build ----------
__global__ void hist_kernel(const int* __restrict__ idx_i, int E, int* __restrict__ counts) {
    int e = blockIdx.x * blockDim.x + threadIdx.x;
    if (e < E) atomicAdd(&counts[idx_i[e]], 1);
}

// single block, 256 threads, A <= 2048 (A=1200 here)
__global__ __launch_bounds__(256) void scan_kernel(const int* __restrict__ counts, int A,
                                                   int* __restrict__ offsets, int* __restrict__ cursor) {
    __shared__ int part[256];
    const int t = threadIdx.x;
    const int base = t * 8;
    int c[8];
    int s = 0;
    #pragma unroll
    for (int p = 0; p < 8; ++p) {
        int idx = base + p;
        c[p] = (idx < A) ? counts[idx] : 0;
        s += c[p];
    }
    part[t] = s;
    __syncthreads();
    #pragma unroll
    for (int off = 1; off < 256; off <<= 1) {
        int v = (t >= off) ? part[t - off] : 0;
        __syncthreads();
        part[t] += v;
        __syncthreads();
    }
    int run = part[t] - s;   // exclusive prefix of this thread's chunk
    #pragma unroll
    for (int p = 0; p < 8; ++p) {
        int idx = base + p;
        if (idx < A) { offsets[idx] = run; cursor[idx] = run; run += c[p]; }
    }
    if (t == 255) offsets[A] = run;   // total = E
}

__global__ void scatter_kernel(const int* __restrict__ idx_i, int E,
                               int* __restrict__ cursor, int* __restrict__ esorted) {
    int e = blockIdx.x * blockDim.x + threadIdx.x;
    if (e < E) {
        int p = atomicAdd(&cursor[idx_i[e]], 1);
        esorted[p] = e;
    }
}

// ---------- main atom kernel ----------
__global__ __launch_bounds__(128) void so3_atom_kernel(
    const float* __restrict__ x,        // [A, 9, 128]
    const float* __restrict__ radial,   // [E, 20]
    const float* __restrict__ dir,      // [E, 3]
    const float* __restrict__ cutoff,   // [E]
    const float* __restrict__ Wf,       // [20, 384]
    const float* __restrict__ bf,       // [384]
    const float* __restrict__ cg_vals,  // [ncg]
    const int* __restrict__ idx_j,      // [E]
    const int* __restrict__ cg_i1,
    const int* __restrict__ cg_i2,
    const int* __restrict__ cg_i3,
    int ncg,
    const int* __restrict__ offsets,    // [A+1]
    const int* __restrict__ esorted,    // [E]
    float* __restrict__ out)            // [A, 9, 128]
{
    const int a = blockIdx.x;
    const int f = threadIdx.x;
    const int start = offsets[a];
    const int end   = offsets[a + 1];

    __shared__ float M[CHUNK][81];   // per-edge 9x9, row-major [s3][s1]
    __shared__ float Ysh[CHUNK][9];
    __shared__ int   els[CHUNK];

    float acc[S9];
    #pragma unroll
    for (int s = 0; s < S9; ++s) acc[s] = 0.0f;

    // per-f filter biases (loop-invariant)
    const float b0 = bf[0 * NF + f];
    const float b1 = bf[1 * NF + f];
    const float b2 = bf[2 * NF + f];

    for (int cs = start; cs < end; cs += CHUNK) {
        const int n = min(CHUNK, end - cs);

        // zero the first n M rows (contiguous)
        for (int q = f; q < n * 81; q += NF) ((float*)M)[q] = 0.0f;

        // thread f < n: fetch edge id + compute its spherical harmonics
        if (f < n) {
            const int e = esorted[cs + f];
            els[f] = e;
            float dx = dir[3 * e], dy = dir[3 * e + 1], dz = dir[3 * e + 2];
            const float inv = rsqrtf(dx * dx + dy * dy + dz * dz);
            dx *= inv; dy *= inv; dz *= inv;
            const float s3c  = 1.7320508075688772f;   // sqrt(3)
            const float s5c  = 2.2360679774997896f;   // sqrt(5)
            const float s15c = 3.8729833462074170f;   // sqrt(15)
            Ysh[f][0] = 1.0f;
            Ysh[f][1] = s3c * dy;
            Ysh[f][2] = s3c * dz;
            Ysh[f][3] = s3c * dx;
            Ysh[f][4] = s15c * dx * dy;
            Ysh[f][5] = s15c * dy * dz;
            Ysh[f][6] = 0.5f * s5c * (3.0f * dz * dz - 1.0f);
            Ysh[f][7] = s15c * dx * dz;
            Ysh[f][8] = 0.5f * s15c * (dx * dx - dy * dy);
        }
        __syncthreads();

        // build all n M matrices (LDS atomics; ncg ~ O(150) spread over 128 threads)
        for (int c = 0; c < n; ++c) {
            for (int k = f; k < ncg; k += NF) {
                atomicAdd(&M[c][cg_i3[k] * S9 + cg_i1[k]], cg_vals[k] * Ysh[c][cg_i2[k]]);
            }
        }
        __syncthreads();

        // contract each edge in the chunk
        for (int c = 0; c < n; ++c) {
            const int e = els[c];

            float rad[NRAD];
            #pragma unroll
            for (int r = 0; r < NRAD; ++r) rad[r] = radial[e * NRAD + r];
            const float cut = cutoff[e];

            float wl0 = b0, wl1 = b1, wl2 = b2;
            #pragma unroll
            for (int r = 0; r < NRAD; ++r) {
                const float* wrow = Wf + r * (3 * NF) + f;
                wl0 = fmaf(rad[r], wrow[0],      wl0);
                wl1 = fmaf(rad[r], wrow[NF],     wl1);
                wl2 = fmaf(rad[r], wrow[2 * NF], wl2);
            }
            wl0 *= cut; wl1 *= cut; wl2 *= cut;

            const int j = idx_j[e];
            const float* xp = x + (size_t)j * (S9 * NF) + f;
            float xj[S9];
            #pragma unroll
            for (int s = 0; s < S9; ++s) xj[s] = xp[s * NF];

            const float* Mc = M[c];
            #pragma unroll
            for (int s3 = 0; s3 < S9; ++s3) {
                float t = 0.0f;
                #pragma unroll
                for (int s1 = 0; s1 < S9; ++s1) t = fmaf(Mc[s3 * S9 + s1], xj[s1], t);
                const float w = (s3 == 0) ? wl0 : ((s3 < 4) ? wl1 : wl2);
                acc[s3] = fmaf(w, t, acc[s3]);
            }
        }
        __syncthreads();   // all reads of M done before next chunk zeroes it
    }

    // single coalesced write per atom — no atomics, overwrites the 0xAA poison
    float* op = out + (size_t)a * (S9 * NF) + f;
    #pragma unroll
    for (int s = 0; s < S9; ++s) op[s * NF] = acc[s];
}

extern "C" void kernel_launch(void* const* d_in, const int* in_sizes, int n_in,
                              void* d_out, int out_size, void* d_ws, size_t ws_size,
                              hipStream_t stream) {
    const float* x       = (const float*)d_in[0];
    const float* radial  = (const float*)d_in[1];
    const float* dir     = (const float*)d_in[2];
    const float* cutoff  = (const float*)d_in[3];
    const float* Wf      = (const float*)d_in[4];
    const float* bf      = (const float*)d_in[5];
    const float* cg_vals = (const float*)d_in[6];
    const int*   idx_i   = (const int*)d_in[7];
    const int*   idx_j   = (const int*)d_in[8];
    const int*   cg_i1   = (const int*)d_in[9];
    const int*   cg_i2   = (const int*)d_in[10];
    const int*   cg_i3   = (const int*)d_in[11];
    // d_in[12] = w_idx: unused — w_idx[k] == l(cg_idx_out[k]), folded into kernel.

    const int E   = in_sizes[7];
    const int ncg = in_sizes[6];
    const int A   = in_sizes[0] / (S9 * NF);

    // workspace layout (ints): counts[A] | offsets[A+1] | cursor[A] | esorted[E]
    int* counts  = (int*)d_ws;
    int* offsets = counts + A;
    int* cursor  = offsets + (A + 1);
    int* esorted = cursor + A;

    hipMemsetAsync(counts, 0, (size_t)A * sizeof(int), stream);

    const int TB = 256;
    hist_kernel<<<(E + TB - 1) / TB, TB, 0, stream>>>(idx_i, E, counts);
    scan_kernel<<<1, 256, 0, stream>>>(counts, A, offsets, cursor);
    scatter_kernel<<<(E + TB - 1) / TB, TB, 0, stream>>>(idx_i, E, cursor, esorted);

    so3_atom_kernel<<<A, NF, 0, stream>>>(
        x, radial, dir, cutoff, Wf, bf, cg_vals,
        idx_j, cg_i1, cg_i2, cg_i3, ncg, offsets, esorted, (float*)d_out);
}

// Round 3
// 126.383 us; speedup vs baseline: 1.1446x; 1.1446x over previous
//
#include <hip/hip_runtime.h>
#include <math.h>

// SO3 convolution lmax=2 — balanced atom-aligned chunks, no float atomics.
//   A) CSR sort edges by destination atom (hist -> scan -> scatter).
//      scan also emits chunk_off[a] = prefix of ceil(deg_a/C): each atom's
//      edges split into chunks of <= C edges -> perfectly balanced blocks.
//   B) phase-B: one 64-thread wave per chunk. Thread owns 2 f-channels
//      (float2). Per edge: M[9][9] (padded rows of 12) built in LDS from
//      sparse CG, dense contraction + per-l radial filter, accumulate.
//      Chunk partial written to a workspace slot with plain stores.
//   C) phase-C: one wave per atom sums its ~2 slots -> out (single write).
//   Fallback: if ws_size can't hold slots, phase-B atomicAdds into out.

#define S9     9
#define MROW   12          // padded M row stride (floats): rows 16B-aligned
#define NF     128
#define NRAD   20
#define CEDGE  8           // edges per chunk

// ---------- helpers ----------
__device__ inline float2 f2fma(float a, float2 b, float2 c) {
    return make_float2(fmaf(a, b.x, c.x), fmaf(a, b.y, c.y));
}

// ---------- CSR build ----------
__global__ void hist_kernel(const int* __restrict__ idx_i, int E, int* __restrict__ counts) {
    int e = blockIdx.x * blockDim.x + threadIdx.x;
    if (e < E) atomicAdd(&counts[idx_i[e]], 1);
}

// single block, 256 threads, A <= 2048
__global__ __launch_bounds__(256) void scan_kernel(const int* __restrict__ counts, int A,
                                                   int* __restrict__ offsets, int* __restrict__ cursor,
                                                   int* __restrict__ chunk_off) {
    __shared__ int part[256];
    const int t = threadIdx.x;
    const int base = t * 8;
    int c[8];
    int s = 0;
    #pragma unroll
    for (int p = 0; p < 8; ++p) {
        int idx = base + p;
        c[p] = (idx < A) ? counts[idx] : 0;
        s += c[p];
    }
    part[t] = s;
    __syncthreads();
    #pragma unroll
    for (int off = 1; off < 256; off <<= 1) {
        int v = (t >= off) ? part[t - off] : 0;
        __syncthreads();
        part[t] += v;
        __syncthreads();
    }
    int run = part[t] - s;
    #pragma unroll
    for (int p = 0; p < 8; ++p) {
        int idx = base + p;
        if (idx < A) { offsets[idx] = run; cursor[idx] = run; run += c[p]; }
    }
    if (t == 255) offsets[A] = run;
    __syncthreads();

    // second scan: chunk offsets (ceil(deg/CEDGE))
    int k[8];
    int s2 = 0;
    #pragma unroll
    for (int p = 0; p < 8; ++p) {
        int idx = base + p;
        k[p] = (idx < A) ? ((c[p] + CEDGE - 1) / CEDGE) : 0;
        s2 += k[p];
    }
    part[t] = s2;
    __syncthreads();
    #pragma unroll
    for (int off = 1; off < 256; off <<= 1) {
        int v = (t >= off) ? part[t - off] : 0;
        __syncthreads();
        part[t] += v;
        __syncthreads();
    }
    int run2 = part[t] - s2;
    #pragma unroll
    for (int p = 0; p < 8; ++p) {
        int idx = base + p;
        if (idx < A) { chunk_off[idx] = run2; run2 += k[p]; }
    }
    if (t == 255) chunk_off[A] = run2;   // total chunk count
}

__global__ void scatter_kernel(const int* __restrict__ idx_i, int E,
                               int* __restrict__ cursor, int* __restrict__ esorted) {
    int e = blockIdx.x * blockDim.x + threadIdx.x;
    if (e < E) {
        int p = atomicAdd(&cursor[idx_i[e]], 1);
        esorted[p] = e;
    }
}

// ---------- phase B: one wave per chunk ----------
__global__ __launch_bounds__(64) void so3_chunk_kernel(
    const float* __restrict__ x,        // [A, 9, 128]
    const float* __restrict__ radial,   // [E, 20]
    const float* __restrict__ dir,      // [E, 3]
    const float* __restrict__ cutoff,   // [E]
    const float* __restrict__ Wf,       // [20, 384]
    const float* __restrict__ bf,       // [384]
    const float* __restrict__ cg_vals,
    const int* __restrict__ idx_j,
    const int* __restrict__ cg_i1,
    const int* __restrict__ cg_i2,
    const int* __restrict__ cg_i3,
    int ncg, int A,
    const int* __restrict__ offsets,    // [A+1]
    const int* __restrict__ chunk_off,  // [A+1]
    const int* __restrict__ esorted,    // [E]
    float* __restrict__ slots,          // [nchunks, 9, 128] (or null)
    float* __restrict__ out,            // [A, 9, 128] (atomic fallback)
    int use_slots)
{
    const int ch = blockIdx.x;
    const int nchunks = chunk_off[A];
    if (ch >= nchunks) return;

    // binary search: atom a with chunk_off[a] <= ch < chunk_off[a+1]
    int lo = 0, hi = A;
    while (hi - lo > 1) {
        int mid = (lo + hi) >> 1;
        if (chunk_off[mid] <= ch) lo = mid; else hi = mid;
    }
    const int a = lo;
    const int q = ch - chunk_off[a];
    const int estart = offsets[a] + q * CEDGE;
    const int n = min(CEDGE, offsets[a + 1] - estart);

    const int t = threadIdx.x;           // f-pair index: f = 2t, 2t+1

    __shared__ __align__(16) float M[CEDGE][MROW * S9];
    __shared__ float Ysh[CEDGE][S9];
    __shared__ int   els[CEDGE];

    // zero M (float4 stores)
    {
        float4* Mz = (float4*)&M[0][0];
        const int tot4 = CEDGE * MROW * S9 / 4;   // 216
        for (int qq = t; qq < tot4; qq += 64) Mz[qq] = make_float4(0.f, 0.f, 0.f, 0.f);
    }
    // edge ids + spherical harmonics
    if (t < n) {
        const int e = esorted[estart + t];
        els[t] = e;
        float dx = dir[3 * e], dy = dir[3 * e + 1], dz = dir[3 * e + 2];
        const float inv = rsqrtf(dx * dx + dy * dy + dz * dz);
        dx *= inv; dy *= inv; dz *= inv;
        const float s3c  = 1.7320508075688772f;
        const float s5c  = 2.2360679774997896f;
        const float s15c = 3.8729833462074170f;
        Ysh[t][0] = 1.0f;
        Ysh[t][1] = s3c * dy;
        Ysh[t][2] = s3c * dz;
        Ysh[t][3] = s3c * dx;
        Ysh[t][4] = s15c * dx * dy;
        Ysh[t][5] = s15c * dy * dz;
        Ysh[t][6] = 0.5f * s5c * (3.0f * dz * dz - 1.0f);
        Ysh[t][7] = s15c * dx * dz;
        Ysh[t][8] = 0.5f * s15c * (dx * dx - dy * dy);
    }
    __syncthreads();

    // build M for all n edges in parallel: 8 threads per edge
    {
        const int c = t >> 3;          // edge within chunk
        const int r = t & 7;
        if (c < n) {
            for (int kk = r; kk < ncg; kk += 8) {
                atomicAdd(&M[c][cg_i3[kk] * MROW + cg_i1[kk]], cg_vals[kk] * Ysh[c][cg_i2[kk]]);
            }
        }
    }
    __syncthreads();

    // contract
    float2 acc[S9];
    #pragma unroll
    for (int s = 0; s < S9; ++s) acc[s] = make_float2(0.f, 0.f);

    const float2 b0 = ((const float2*)(bf + 0 * NF))[t];
    const float2 b1 = ((const float2*)(bf + 1 * NF))[t];
    const float2 b2 = ((const float2*)(bf + 2 * NF))[t];

    for (int c = 0; c < n; ++c) {
        int e = __builtin_amdgcn_readfirstlane(els[c]);
        const int j = __builtin_amdgcn_readfirstlane(idx_j[e]);
        const float cut = cutoff[e];

        float rad[NRAD];
        #pragma unroll
        for (int r = 0; r < NRAD; ++r) rad[r] = radial[e * NRAD + r];

        float2 wl0 = b0, wl1 = b1, wl2 = b2;
        #pragma unroll
        for (int r = 0; r < NRAD; ++r) {
            const float2* wrow = (const float2*)(Wf + r * (3 * NF));
            wl0 = f2fma(rad[r], wrow[t],            wl0);
            wl1 = f2fma(rad[r], wrow[t + 64],       wl1);
            wl2 = f2fma(rad[r], wrow[t + 128],      wl2);
        }
        wl0.x *= cut; wl0.y *= cut; wl1.x *= cut; wl1.y *= cut; wl2.x *= cut; wl2.y *= cut;

        const float2* xp = (const float2*)(x + (size_t)j * (S9 * NF)) + t;
        float2 xj[S9];
        #pragma unroll
        for (int s = 0; s < S9; ++s) xj[s] = xp[s * 64];

        #pragma unroll
        for (int s3 = 0; s3 < S9; ++s3) {
            const float4* mr = (const float4*)&M[c][s3 * MROW];
            const float4 m0 = mr[0];
            const float4 m1 = mr[1];
            const float  m8 = M[c][s3 * MROW + 8];
            float2 tsum = make_float2(0.f, 0.f);
            tsum = f2fma(m0.x, xj[0], tsum);
            tsum = f2fma(m0.y, xj[1], tsum);
            tsum = f2fma(m0.z, xj[2], tsum);
            tsum = f2fma(m0.w, xj[3], tsum);
            tsum = f2fma(m1.x, xj[4], tsum);
            tsum = f2fma(m1.y, xj[5], tsum);
            tsum = f2fma(m1.z, xj[6], tsum);
            tsum = f2fma(m1.w, xj[7], tsum);
            tsum = f2fma(m8,   xj[8], tsum);
            const float2 w = (s3 == 0) ? wl0 : ((s3 < 4) ? wl1 : wl2);
            acc[s3].x = fmaf(w.x, tsum.x, acc[s3].x);
            acc[s3].y = fmaf(w.y, tsum.y, acc[s3].y);
        }
    }

    if (use_slots) {
        float2* sp = (float2*)(slots + (size_t)ch * (S9 * NF)) + t;
        #pragma unroll
        for (int s = 0; s < S9; ++s) sp[s * 64] = acc[s];
    } else {
        float* op = out + (size_t)a * (S9 * NF) + 2 * t;
        #pragma unroll
        for (int s = 0; s < S9; ++s) {
            atomicAdd(&op[s * NF],     acc[s].x);
            atomicAdd(&op[s * NF + 1], acc[s].y);
        }
    }
}

// ---------- phase C: one wave per atom sums its slots ----------
__global__ __launch_bounds__(64) void so3_reduce_kernel(
    const float* __restrict__ slots, const int* __restrict__ chunk_off,
    float* __restrict__ out)
{
    const int a = blockIdx.x;
    const int t = threadIdx.x;
    const int c0 = chunk_off[a];
    const int c1 = chunk_off[a + 1];

    float2 acc[S9];
    #pragma unroll
    for (int s = 0; s < S9; ++s) acc[s] = make_float2(0.f, 0.f);

    for (int ch = c0; ch < c1; ++ch) {
        const float2* sp = (const float2*)(slots + (size_t)ch * (S9 * NF)) + t;
        #pragma unroll
        for (int s = 0; s < S9; ++s) {
            float2 v = sp[s * 64];
            acc[s].x += v.x; acc[s].y += v.y;
        }
    }
    float2* op = (float2*)(out + (size_t)a * (S9 * NF)) + t;
    #pragma unroll
    for (int s = 0; s < S9; ++s) op[s * 64] = acc[s];
}

extern "C" void kernel_launch(void* const* d_in, const int* in_sizes, int n_in,
                              void* d_out, int out_size, void* d_ws, size_t ws_size,
                              hipStream_t stream) {
    const float* x       = (const float*)d_in[0];
    const float* radial  = (const float*)d_in[1];
    const float* dir     = (const float*)d_in[2];
    const float* cutoff  = (const float*)d_in[3];
    const float* Wf      = (const float*)d_in[4];
    const float* bf      = (const float*)d_in[5];
    const float* cg_vals = (const float*)d_in[6];
    const int*   idx_i   = (const int*)d_in[7];
    const int*   idx_j   = (const int*)d_in[8];
    const int*   cg_i1   = (const int*)d_in[9];
    const int*   cg_i2   = (const int*)d_in[10];
    const int*   cg_i3   = (const int*)d_in[11];
    // d_in[12] = w_idx: unused (w_idx[k] == l(cg_idx_out[k]), folded into kernel)

    const int E   = in_sizes[7];
    const int ncg = in_sizes[6];
    const int A   = in_sizes[0] / (S9 * NF);

    // ws ints: counts[A] | offsets[A+1] | cursor[A] | chunk_off[A+1] | esorted[E]
    int* counts    = (int*)d_ws;
    int* offsets   = counts + A;
    int* cursor    = offsets + (A + 1);
    int* chunk_off = cursor + A;
    int* esorted   = chunk_off + (A + 1);
    size_t int_bytes = (size_t)(4 * A + 2 + E) * sizeof(int);
    size_t slots_off = (int_bytes + 255) & ~(size_t)255;

    const int max_chunks = E / CEDGE + A;   // upper bound on total chunks
    size_t slots_bytes = (size_t)max_chunks * (S9 * NF) * sizeof(float);
    const int use_slots = (ws_size >= slots_off + slots_bytes) ? 1 : 0;
    float* slots = (float*)((char*)d_ws + slots_off);
    float* out   = (float*)d_out;

    hipMemsetAsync(counts, 0, (size_t)A * sizeof(int), stream);

    const int TB = 256;
    hist_kernel<<<(E + TB - 1) / TB, TB, 0, stream>>>(idx_i, E, counts);
    scan_kernel<<<1, 256, 0, stream>>>(counts, A, offsets, cursor, chunk_off);
    scatter_kernel<<<(E + TB - 1) / TB, TB, 0, stream>>>(idx_i, E, cursor, esorted);

    if (!use_slots) {
        // atomic fallback needs zeroed output
        hipMemsetAsync(out, 0, (size_t)out_size * sizeof(float), stream);
    }

    so3_chunk_kernel<<<max_chunks, 64, 0, stream>>>(
        x, radial, dir, cutoff, Wf, bf, cg_vals, idx_j,
        cg_i1, cg_i2, cg_i3, ncg, A, offsets, chunk_off, esorted,
        slots, out, use_slots);

    if (use_slots) {
        so3_reduce_kernel<<<A, 64, 0, stream>>>(slots, chunk_off, out);
    }
}